// Round 1
// baseline (331.837 us; speedup 1.0000x reference)
//
#include <hip/hip_runtime.h>
#include <math.h>

// EEG connectivity: B=4, C=64, T=2048, FS=256, 6 bands, 7 features.
// Band k-ranges (rfft bins, inclusive): freqs = k/8 Hz.
__constant__ int c_klo[6] = {4, 4, 32, 64, 104, 240};
__constant__ int c_nk[6]  = {357, 29, 33, 41, 137, 121};

#define PI2_N 0.0030679615757712823f /* 2*pi/2048 */

// ---------------- K0: exact twiddle table twid[k-4][t] = exp(+i*2pi*k*t/2048)
__global__ __launch_bounds__(256) void k_twid(float2* __restrict__ twid) {
  int idx = blockIdx.x * 256 + threadIdx.x;  // 357*2048 = 731136 entries exactly
  int k = 4 + (idx >> 11);
  int t = idx & 2047;
  int m = (k * t) & 2047;
  float s, c;
  sincosf((float)m * PI2_N, &s, &c);
  twid[idx] = make_float2(c, s);
}

// ---------------- K1: band-limited forward DFT of both inputs.
// coef[(bside*357+kidx)*64+ch] = F[k] (float2); pwr = |F|^2 (float).
__global__ __launch_bounds__(256) void k_dft(const float* __restrict__ e1,
                                             const float* __restrict__ e2,
                                             float2* __restrict__ coef,
                                             float* __restrict__ pwr) {
  __shared__ float xs[2048];
  __shared__ float red[4][64][2];
  int sig = blockIdx.x;              // 512 = b(4) x side(2) x ch(64)
  int b = sig >> 7, side = (sig >> 6) & 1, ch = sig & 63;
  int bside = b * 2 + side;
  const float* src = (side ? e2 : e1) + (size_t)(b * 64 + ch) * 2048;
  for (int q = 0; q < 2; ++q) {
    int i4 = q * 256 + threadIdx.x;
    ((float4*)xs)[i4] = ((const float4*)src)[i4];
  }
  __syncthreads();
  int binlane = threadIdx.x & 63, tch = threadIdx.x >> 6;
  int t0 = tch << 9;  // 512-sample chunk per thread
  const float* xp = xs + t0;
  for (int rnd = 0; rnd < 6; ++rnd) {
    int kidx = rnd * 64 + binlane;
    int k = kidx + 4;
    float wr, wi, sr, si;
    sincosf(-(float)((k * t0) & 2047) * PI2_N, &wi, &wr);  // w = e^{-i*2pi*k*t0/2048}
    sincosf(-(float)k * PI2_N, &si, &sr);                  // step = e^{-i*2pi*k/2048}
    float are = 0.f, aim = 0.f;
    for (int tt = 0; tt < 512; tt += 4) {
      float4 xv = *(const float4*)(xp + tt);
      float nr, ni;
      are = fmaf(xv.x, wr, are); aim = fmaf(xv.x, wi, aim);
      nr = fmaf(wr, sr, -(wi * si)); ni = fmaf(wr, si, wi * sr); wr = nr; wi = ni;
      are = fmaf(xv.y, wr, are); aim = fmaf(xv.y, wi, aim);
      nr = fmaf(wr, sr, -(wi * si)); ni = fmaf(wr, si, wi * sr); wr = nr; wi = ni;
      are = fmaf(xv.z, wr, are); aim = fmaf(xv.z, wi, aim);
      nr = fmaf(wr, sr, -(wi * si)); ni = fmaf(wr, si, wi * sr); wr = nr; wi = ni;
      are = fmaf(xv.w, wr, are); aim = fmaf(xv.w, wi, aim);
      nr = fmaf(wr, sr, -(wi * si)); ni = fmaf(wr, si, wi * sr); wr = nr; wi = ni;
    }
    red[tch][binlane][0] = are;
    red[tch][binlane][1] = aim;
    __syncthreads();
    if (tch == 0 && kidx < 357) {
      float rr = red[0][binlane][0] + red[1][binlane][0] + red[2][binlane][0] + red[3][binlane][0];
      float ri = red[0][binlane][1] + red[1][binlane][1] + red[2][binlane][1] + red[3][binlane][1];
      int a = (bside * 357 + kidx) * 64 + ch;
      coef[a] = make_float2(rr, ri);
      pwr[a] = rr * rr + ri * ri;
    }
    __syncthreads();
  }
}

// ---------------- K2: inverse band DFT -> analytic signal -> fields + stats.
// fields[((band*8+bside)*4 + f)*131072 + t*64 + ch], f: 0=phi 1=cos 2=sin 3=f
// statp[((band*8+bside)*64 + tchunk)*64 + ch]*3 = partial {Sum f, Sum f^2, Sum f^4}
__global__ __launch_bounds__(256) void k_analytic(const float2* __restrict__ coef,
                                                  const float2* __restrict__ twid,
                                                  float* __restrict__ fields,
                                                  float* __restrict__ statp) {
  __shared__ float Fs[64 * 128];  // [kk][ch][2]  (32 KB)
  __shared__ float tws[64 * 64];  // [kk][tl][2], tl<32 (16 KB)
  int tchunk = blockIdx.x, bside = blockIdx.y, band = blockIdx.z;
  int ch = threadIdx.x & 63, tg = threadIdx.x >> 6;  // wave-uniform tg
  int kloB = c_klo[band], n = c_nk[band];
  int tbase = tchunk * 32;
  float ar[8], ai[8];
#pragma unroll
  for (int r = 0; r < 8; ++r) { ar[r] = 0.f; ai[r] = 0.f; }
  for (int c0 = 0; c0 < n; c0 += 64) {
    int kc = min(64, n - c0);
    int k0 = kloB + c0;
    int cbase = (bside * 357 + (k0 - 4)) * 64;  // float2 units
    for (int idx = threadIdx.x; idx < kc * 32; idx += 256)
      ((float4*)Fs)[idx] = ((const float4*)(coef + cbase))[idx];
    int tw0 = (k0 - 4) * 2048 + tbase;
    for (int idx = threadIdx.x; idx < kc * 32; idx += 256) {
      int kk = idx >> 5, tl = idx & 31;
      float2 v = twid[kk * 2048 + tw0 + tl];
      ((float2*)tws)[kk * 32 + tl] = v;
    }
    __syncthreads();
    const float* fp = Fs + ch * 2;
    const float4* twq = (const float4*)tws + tg * 4;
    for (int kk = 0; kk < kc; ++kk) {
      float Fre = fp[kk * 128], Fim = fp[kk * 128 + 1];
      float4 q0 = twq[kk * 16 + 0];
      float4 q1 = twq[kk * 16 + 1];
      float4 q2 = twq[kk * 16 + 2];
      float4 q3 = twq[kk * 16 + 3];
      ar[0] = fmaf(Fre, q0.x, fmaf(-Fim, q0.y, ar[0])); ai[0] = fmaf(Fre, q0.y, fmaf(Fim, q0.x, ai[0]));
      ar[1] = fmaf(Fre, q0.z, fmaf(-Fim, q0.w, ar[1])); ai[1] = fmaf(Fre, q0.w, fmaf(Fim, q0.z, ai[1]));
      ar[2] = fmaf(Fre, q1.x, fmaf(-Fim, q1.y, ar[2])); ai[2] = fmaf(Fre, q1.y, fmaf(Fim, q1.x, ai[2]));
      ar[3] = fmaf(Fre, q1.z, fmaf(-Fim, q1.w, ar[3])); ai[3] = fmaf(Fre, q1.w, fmaf(Fim, q1.z, ai[3]));
      ar[4] = fmaf(Fre, q2.x, fmaf(-Fim, q2.y, ar[4])); ai[4] = fmaf(Fre, q2.y, fmaf(Fim, q2.x, ai[4]));
      ar[5] = fmaf(Fre, q2.z, fmaf(-Fim, q2.w, ar[5])); ai[5] = fmaf(Fre, q2.w, fmaf(Fim, q2.z, ai[5]));
      ar[6] = fmaf(Fre, q3.x, fmaf(-Fim, q3.y, ar[6])); ai[6] = fmaf(Fre, q3.y, fmaf(Fim, q3.x, ai[6]));
      ar[7] = fmaf(Fre, q3.z, fmaf(-Fim, q3.w, ar[7])); ai[7] = fmaf(Fre, q3.w, fmaf(Fim, q3.z, ai[7]));
    }
    __syncthreads();
  }
  float sf = 0.f, sf2 = 0.f, sf4 = 0.f;
  int pbase = (band * 8 + bside) * 4;
  int toff = (tbase + tg * 8) * 64 + ch;
  float* fphi = fields + (size_t)(pbase + 0) * 131072 + toff;
  float* fcos = fields + (size_t)(pbase + 1) * 131072 + toff;
  float* fsin = fields + (size_t)(pbase + 2) * 131072 + toff;
  float* ffil = fields + (size_t)(pbase + 3) * 131072 + toff;
#pragma unroll
  for (int r = 0; r < 8; ++r) {
    float re = ar[r] * (1.f / 1024.f), im = ai[r] * (1.f / 1024.f);  // *2/T
    float mag2 = re * re + im * im;
    float rinv = mag2 > 0.f ? rsqrtf(mag2) : 0.f;
    float cc = mag2 > 0.f ? re * rinv : 1.f;
    float ss = im * rinv;
    float ph = atan2f(im, re);
    fphi[r * 64] = ph; fcos[r * 64] = cc; fsin[r * 64] = ss; ffil[r * 64] = re;
    float p = re * re;
    sf += re; sf2 += p; sf4 += p * p;
  }
  float* red = Fs;  // reuse (post final barrier)
  red[(tg * 64 + ch) * 3 + 0] = sf;
  red[(tg * 64 + ch) * 3 + 1] = sf2;
  red[(tg * 64 + ch) * 3 + 2] = sf4;
  __syncthreads();
  if (tg == 0) {
    float a0 = red[ch * 3] + red[(64 + ch) * 3] + red[(128 + ch) * 3] + red[(192 + ch) * 3];
    float a1 = red[ch * 3 + 1] + red[(64 + ch) * 3 + 1] + red[(128 + ch) * 3 + 1] + red[(192 + ch) * 3 + 1];
    float a2 = red[ch * 3 + 2] + red[(64 + ch) * 3 + 2] + red[(128 + ch) * 3 + 2] + red[(192 + ch) * 3 + 2];
    int o = (((band * 8 + bside) * 64 + tchunk) * 64 + ch) * 3;
    statp[o] = a0; statp[o + 1] = a1; statp[o + 2] = a2;
  }
}

// ---------------- K3: reduce per-signal stats over 64 t-chunks.
__global__ __launch_bounds__(256) void k_statred(const float* __restrict__ statp,
                                                 float* __restrict__ stats) {
  int gid = blockIdx.x * 256 + threadIdx.x;  // 3072 = 6*8*64
  int band = gid >> 9, bsd = (gid >> 6) & 7, ch = gid & 63;
  float s0 = 0.f, s1 = 0.f, s2 = 0.f;
  const float* p = statp + ((size_t)(band * 8 + bsd) * 64 * 64 + ch) * 3;
  for (int tc = 0; tc < 64; ++tc) { s0 += p[tc * 192]; s1 += p[tc * 192 + 1]; s2 += p[tc * 192 + 2]; }
  float* o = stats + (size_t)gid * 3;
  o[0] = s0; o[1] = s1; o[2] = s2;
}

// ---------------- K4: fused pairwise accumulations (8 sums), T split 16x.
// part[((bb*16+ts)*8 + a)*4096 + i*64 + j]
__global__ __launch_bounds__(256) void k_pairs(const float* __restrict__ fields,
                                               float* __restrict__ part) {
  __shared__ float li[4 * 16 * 32];  // [f][tt][cc] i-side (8 KB)
  __shared__ float lj[4 * 16 * 64];  // [f][tt][cc] j-side (16 KB)
  int ts = blockIdx.x, itile = blockIdx.y, bb = blockIdx.z;
  int band = bb >> 2, b = bb & 3;
  int tid = threadIdx.x;
  int ti = tid >> 4, tj = tid & 15;
  const float* pi = fields + (size_t)((band * 8 + b * 2 + 0) * 4) * 131072;
  const float* pj = fields + (size_t)((band * 8 + b * 2 + 1) * 4) * 131072;
  float aP[2][4], aQ[2][4], aSg[2][4], aS1[2][4], aS2[2][4], aAp[2][4], aPp[2][4], aFf[2][4];
#pragma unroll
  for (int il = 0; il < 2; ++il)
#pragma unroll
    for (int jl = 0; jl < 4; ++jl) {
      aP[il][jl] = 0.f; aQ[il][jl] = 0.f; aSg[il][jl] = 0.f; aS1[il][jl] = 0.f;
      aS2[il][jl] = 0.f; aAp[il][jl] = 0.f; aPp[il][jl] = 0.f; aFf[il][jl] = 0.f;
    }
  int tb = ts * 128;
  for (int sub = 0; sub < 8; ++sub) {
    int t0 = tb + sub * 16;
#pragma unroll
    for (int q = 0; q < 2; ++q) {
      int fl = (q * 256 + tid) * 4;
      int f = fl >> 9, tt = (fl >> 5) & 15, cc = fl & 31;
      *(float4*)&li[fl] = *(const float4*)(pi + (size_t)f * 131072 + (t0 + tt) * 64 + itile * 32 + cc);
    }
#pragma unroll
    for (int q = 0; q < 4; ++q) {
      int fl = (q * 256 + tid) * 4;
      int f = fl >> 10, tt = (fl >> 6) & 15, cc = fl & 63;
      *(float4*)&lj[fl] = *(const float4*)(pj + (size_t)f * 131072 + (t0 + tt) * 64 + cc);
    }
    __syncthreads();
#pragma unroll 2
    for (int tt = 0; tt < 16; ++tt) {
      float2 ph1 = *(const float2*)&li[tt * 32 + ti * 2];
      float2 c1 = *(const float2*)&li[512 + tt * 32 + ti * 2];
      float2 s1 = *(const float2*)&li[1024 + tt * 32 + ti * 2];
      float2 f1 = *(const float2*)&li[1536 + tt * 32 + ti * 2];
      float4 ph2 = *(const float4*)&lj[tt * 64 + tj * 4];
      float4 c2 = *(const float4*)&lj[1024 + tt * 64 + tj * 4];
      float4 s2 = *(const float4*)&lj[2048 + tt * 64 + tj * 4];
      float4 f2 = *(const float4*)&lj[3072 + tt * 64 + tj * 4];
      float ph1a[2] = {ph1.x, ph1.y}, c1a[2] = {c1.x, c1.y}, s1a[2] = {s1.x, s1.y}, f1a[2] = {f1.x, f1.y};
      float ph2a[4] = {ph2.x, ph2.y, ph2.z, ph2.w};
      float c2a[4] = {c2.x, c2.y, c2.z, c2.w};
      float s2a[4] = {s2.x, s2.y, s2.z, s2.w};
      float f2a[4] = {f2.x, f2.y, f2.z, f2.w};
      float p1a[2] = {f1a[0] * f1a[0], f1a[1] * f1a[1]};
      float n1a[2] = {-p1a[0], -p1a[1]};
      float p2a[4] = {f2a[0] * f2a[0], f2a[1] * f2a[1], f2a[2] * f2a[2], f2a[3] * f2a[3]};
      float n2a[4] = {-p2a[0], -p2a[1], -p2a[2], -p2a[3]};
#pragma unroll
      for (int il = 0; il < 2; ++il) {
#pragma unroll
        for (int jl = 0; jl < 4; ++jl) {
          float pd = ph1a[il] - ph2a[jl];
          bool pos = pd > 0.f;
          aSg[il][jl] += pos ? 1.f : -1.f;
          aS1[il][jl] += pos ? p1a[il] : n1a[il];
          aS2[il][jl] += pos ? p2a[jl] : n2a[jl];
          aAp[il][jl] += fabsf(pd);
          aP[il][jl] = fmaf(c1a[il], c2a[jl], aP[il][jl]);
          aP[il][jl] = fmaf(s1a[il], s2a[jl], aP[il][jl]);
          aQ[il][jl] = fmaf(s1a[il], c2a[jl], aQ[il][jl]);
          aQ[il][jl] = fmaf(-c1a[il], s2a[jl], aQ[il][jl]);
          aPp[il][jl] = fmaf(p1a[il], p2a[jl], aPp[il][jl]);
          aFf[il][jl] = fmaf(f1a[il], f2a[jl], aFf[il][jl]);
        }
      }
    }
    __syncthreads();
  }
  int pb = (bb * 16 + ts) * 8;
#pragma unroll
  for (int il = 0; il < 2; ++il) {
    int ro = itile * 2048 + (ti * 2 + il) * 64 + tj * 4;
    *(float4*)&part[(size_t)(pb + 0) * 4096 + ro] = make_float4(aP[il][0], aP[il][1], aP[il][2], aP[il][3]);
    *(float4*)&part[(size_t)(pb + 1) * 4096 + ro] = make_float4(aQ[il][0], aQ[il][1], aQ[il][2], aQ[il][3]);
    *(float4*)&part[(size_t)(pb + 2) * 4096 + ro] = make_float4(aSg[il][0], aSg[il][1], aSg[il][2], aSg[il][3]);
    *(float4*)&part[(size_t)(pb + 3) * 4096 + ro] = make_float4(aS1[il][0], aS1[il][1], aS1[il][2], aS1[il][3]);
    *(float4*)&part[(size_t)(pb + 4) * 4096 + ro] = make_float4(aS2[il][0], aS2[il][1], aS2[il][2], aS2[il][3]);
    *(float4*)&part[(size_t)(pb + 5) * 4096 + ro] = make_float4(aAp[il][0], aAp[il][1], aAp[il][2], aAp[il][3]);
    *(float4*)&part[(size_t)(pb + 6) * 4096 + ro] = make_float4(aPp[il][0], aPp[il][1], aPp[il][2], aPp[il][3]);
    *(float4*)&part[(size_t)(pb + 7) * 4096 + ro] = make_float4(aFf[il][0], aFf[il][1], aFf[il][2], aFf[il][3]);
  }
}

// ---------------- K5: reduce partials + coherence + finalize 7 features.
__global__ __launch_bounds__(256) void k_final(const float* __restrict__ part,
                                               const float* __restrict__ stats,
                                               const float* __restrict__ pwr,
                                               float* __restrict__ out) {
  int gid = blockIdx.x * 256 + threadIdx.x;  // 98304 = 24*4096
  int bb = gid >> 12, rem = gid & 4095;
  int band = bb >> 2, b = bb & 3;
  int i = rem >> 6, j = rem & 63;
  float S[8];
#pragma unroll
  for (int a = 0; a < 8; ++a) S[a] = 0.f;
  const float* pp = part + (size_t)bb * 16 * 8 * 4096 + rem;
  for (int ts = 0; ts < 16; ++ts)
#pragma unroll
    for (int a = 0; a < 8; ++a) S[a] += pp[(ts * 8 + a) * 4096];
  const float* st1 = stats + (size_t)((band * 8 + b * 2 + 0) * 64 + i) * 3;
  const float* st2 = stats + (size_t)((band * 8 + b * 2 + 1) * 64 + j) * 3;
  float sf1 = st1[0], sp1 = st1[1], sq1 = st1[2];
  float sf2 = st2[0], sp2 = st2[1], sq2 = st2[2];
  const float T = 2048.f, Ti = 1.f / 2048.f, Vi = 1.f / 2047.f;
  float plv = sqrtf(S[0] * S[0] + S[1] * S[1]) * Ti;
  float pli = fabsf(S[2]) * Ti;
  float wpli = fabsf(0.5f * (S[3] + S[4])) / (0.5f * (sp1 + sp2) + 1e-8f);
  int kl = c_klo[band] - 4, n = c_nk[band];
  const float* P1 = pwr + ((b * 2 + 0) * 357 + kl) * 64 + i;
  const float* P2 = pwr + ((b * 2 + 1) * 357 + kl) * 64 + j;
  float coh = 0.f;
  for (int kk = 0; kk < n; ++kk) {
    float r = P1[kk * 64] * P2[kk * 64];
    coh += __fdividef(r, r + 1e-8f);
  }
  coh *= (1.f / 1025.f);
  float mp1 = sp1 * Ti, mp2 = sp2 * Ti;
  float sd1 = sqrtf(fmaxf((sq1 - T * mp1 * mp1) * Vi, 0.f));
  float sd2 = sqrtf(fmaxf((sq2 - T * mp2 * mp2) * Vi, 0.f));
  float pcorr = (S[6] - T * mp1 * mp2) / ((sd1 + 1e-8f) * (sd2 + 1e-8f)) * Ti;
  float phd = S[5] * Ti;
  float mf1 = sf1 * Ti, mf2 = sf2 * Ti;
  float se1 = sqrtf(fmaxf((sp1 - T * mf1 * mf1) * Vi, 0.f));
  float se2 = sqrtf(fmaxf((sp2 - T * mf2 * mf2) * Vi, 0.f));
  float tcorr = (S[7] - T * mf1 * mf2) / ((se1 + 1e-8f) * (se2 + 1e-8f)) * Ti;
  size_t ob = (size_t)((b * 6 + band) * 7) * 4096 + rem;
  out[ob] = plv;
  out[ob + 4096] = pli;
  out[ob + 2 * 4096] = wpli;
  out[ob + 3 * 4096] = coh;
  out[ob + 4 * 4096] = pcorr;
  out[ob + 5 * 4096] = phd;
  out[ob + 6 * 4096] = tcorr;
}

extern "C" void kernel_launch(void* const* d_in, const int* in_sizes, int n_in,
                              void* d_out, int out_size, void* d_ws, size_t ws_size,
                              hipStream_t stream) {
  const float* e1 = (const float*)d_in[0];
  const float* e2 = (const float*)d_in[1];
  float* out = (float*)d_out;
  char* ws = (char*)d_ws;
  size_t off = 0;
  auto alloc = [&](size_t bytes) -> void* {
    void* p = ws + off;
    off += (bytes + 255) & ~(size_t)255;
    return p;
  };
  float2* twid = (float2*)alloc((size_t)357 * 2048 * 8);            // 5.85 MB
  float2* coef = (float2*)alloc((size_t)8 * 357 * 64 * 8);          // 1.46 MB
  float* pwr = (float*)alloc((size_t)8 * 357 * 64 * 4);             // 0.73 MB
  float* fields = (float*)alloc((size_t)6 * 8 * 4 * 2048 * 64 * 4); // 100.7 MB
  float* statp = (float*)alloc((size_t)6 * 8 * 64 * 64 * 3 * 4);    // 2.36 MB
  float* stats = (float*)alloc((size_t)6 * 8 * 64 * 3 * 4);         // 37 KB
  float* part = (float*)alloc((size_t)24 * 16 * 8 * 4096 * 4);      // 50.3 MB
  (void)in_sizes; (void)n_in; (void)out_size; (void)ws_size;

  hipLaunchKernelGGL(k_twid, dim3(2856), dim3(256), 0, stream, twid);
  hipLaunchKernelGGL(k_dft, dim3(512), dim3(256), 0, stream, e1, e2, coef, pwr);
  hipLaunchKernelGGL(k_analytic, dim3(64, 8, 6), dim3(256), 0, stream, coef, twid, fields, statp);
  hipLaunchKernelGGL(k_statred, dim3(12), dim3(256), 0, stream, statp, stats);
  hipLaunchKernelGGL(k_pairs, dim3(16, 2, 24), dim3(256), 0, stream, fields, part);
  hipLaunchKernelGGL(k_final, dim3(384), dim3(256), 0, stream, part, stats, pwr, out);
}